// Round 14
// baseline (458.649 us; speedup 1.0000x reference)
//
#include <hip/hip_runtime.h>
#include <math.h>

// World-model (pinned R13): np fp32 ref, structure confirmed — flips confined
// to rounding-ambiguous set. R14 single change: the (0,1,3)-axis reduce is
// emulated as numpy's BUFFERED reduce — per channel e, the (t,b,v) elements
// are gathered e-outermost into 8192-element chunks (buffersize), each chunk
// summed by the full recursive pairwise_sum (64 leaves x 128-elem 8-acc
// blocks, balanced tree), chunks accumulated sequentially (25 chunks).
// einsum = SOP (baseline einsum_sumprod, no FMA); rstd = fdiv(1, fsqrt(s)).
constexpr int T = 16, B = 512, C = 2, V = 25, E = 256;
constexpr int EV  = E * V;           // 6400
constexpr int BEV = B * EV;          // 3,276,800
constexpr int XT  = B * C * V;       // 25600 floats between t-slices of x
constexpr int NB  = 1600;            // 128-element blocks per channel
constexpr int CHUNKS = 25;           // 204800 / 8192
constexpr int BPC = 64;              // 128-blocks per 8192-chunk
constexpr float NF = 204800.0f;

#define WS_M32(ws) ((float*)(ws))
#define WS_R32(ws) ((float*)(ws) + E)

// y(q) for channel e: q in [0,204800) flattens (row=(t,b), v): row=q/25.
__device__ __forceinline__ float yval(const float* __restrict__ x,
                                      float w0, float w1, int q) {
    int row = q / 25;
    int v   = q - row * 25;
    int bse = row * 50 + v;
    return __fadd_rn(__fmul_rn(w0, x[bse]), __fmul_rn(w1, x[bse + 25]));  // SOP
}

// One block per channel e.
__global__ void __launch_bounds__(256) k_stats(const float* __restrict__ x,
                                               const float* __restrict__ W,
                                               float* __restrict__ ws) {
    __shared__ float bs[NB];         // 128-block partial sums (6.4 KB)
    __shared__ float s_mean;
    int e = blockIdx.x;
    float w0 = W[e * 2 + 0];
    float w1 = W[e * 2 + 1];

    // ================= pass 1: mean =================
    for (int p = threadIdx.x; p < NB; p += 256) {
        int q0 = p * 128;
        float r[8];
        #pragma unroll
        for (int j = 0; j < 8; j++) r[j] = yval(x, w0, w1, q0 + j);
        for (int i = 8; i < 128; i += 8) {
            #pragma unroll
            for (int j = 0; j < 8; j++)
                r[j] = __fadd_rn(r[j], yval(x, w0, w1, q0 + i + j));
        }
        bs[p] = __fadd_rn(__fadd_rn(__fadd_rn(r[0],r[1]), __fadd_rn(r[2],r[3])),
                          __fadd_rn(__fadd_rn(r[4],r[5]), __fadd_rn(r[6],r[7])));
    }
    __syncthreads();
    if (threadIdx.x == 0) {
        float acc = 0.0f;            // identity init; 0 + s == s exactly
        for (int c = 0; c < CHUNKS; c++) {
            float t[BPC];
            for (int i = 0; i < BPC; i++) t[i] = bs[c * BPC + i];
            for (int m = BPC / 2; m >= 1; m >>= 1)          // balanced tree ==
                for (int i = 0; i < m; i++)                 // numpy recursion
                    t[i] = __fadd_rn(t[2 * i], t[2 * i + 1]);
            acc = __fadd_rn(acc, t[0]);                     // io1 += chunk
        }
        s_mean = __fdiv_rn(acc, NF);
    }
    __syncthreads();
    float mn = s_mean;

    // ================= pass 2: var =================
    for (int p = threadIdx.x; p < NB; p += 256) {
        int q0 = p * 128;
        float r[8];
        #pragma unroll
        for (int j = 0; j < 8; j++) {
            float d = __fsub_rn(yval(x, w0, w1, q0 + j), mn);
            r[j] = __fmul_rn(d, d);
        }
        for (int i = 8; i < 128; i += 8) {
            #pragma unroll
            for (int j = 0; j < 8; j++) {
                float d = __fsub_rn(yval(x, w0, w1, q0 + i + j), mn);
                r[j] = __fadd_rn(r[j], __fmul_rn(d, d));
            }
        }
        bs[p] = __fadd_rn(__fadd_rn(__fadd_rn(r[0],r[1]), __fadd_rn(r[2],r[3])),
                          __fadd_rn(__fadd_rn(r[4],r[5]), __fadd_rn(r[6],r[7])));
    }
    __syncthreads();
    if (threadIdx.x == 0) {
        float acc = 0.0f;
        for (int c = 0; c < CHUNKS; c++) {
            float t[BPC];
            for (int i = 0; i < BPC; i++) t[i] = bs[c * BPC + i];
            for (int m = BPC / 2; m >= 1; m >>= 1)
                for (int i = 0; i < m; i++)
                    t[i] = __fadd_rn(t[2 * i], t[2 * i + 1]);
            acc = __fadd_rn(acc, t[0]);
        }
        float var = __fdiv_rn(acc, NF);
        WS_M32(ws)[e] = mn;
        WS_R32(ws)[e] = __fdiv_rn(1.0f, __fsqrt_rn(__fadd_rn(var, 1e-5f)));
    }
}

__global__ void __launch_bounds__(256) k_main(const float* __restrict__ x,
                                              const float* __restrict__ W,
                                              const float* __restrict__ g,
                                              const float* __restrict__ bb,
                                              const float* __restrict__ ws,
                                              float* __restrict__ out) {
    int idx = blockIdx.x * 256 + threadIdx.x;   // grid covers BEV exactly
    int b   = idx / EV;
    int rem = idx - b * EV;
    int e   = rem / V;
    int v   = rem - e * V;
    float w0 = W[e * 2 + 0];
    float w1 = W[e * 2 + 1];
    float mn = WS_M32(ws)[e];
    float rs = WS_R32(ws)[e];
    float ga = g[e];                 // == 1.0f: exact no-op
    float be = bb[e];                // == 0.0f: exact no-op
    int xb = b * (C * V) + v;
    float vm = 0.0f;
    #pragma unroll
    for (int t = 0; t < T; t++) {
        float x0 = x[xb + t * XT];
        float x1 = x[xb + t * XT + V];
        float y = __fadd_rn(__fmul_rn(w0, x0), __fmul_rn(w1, x1)); // einsum SOP
        y = __fmul_rn(__fsub_rn(y, mn), rs);                       // (y-mean)*rstd
        y = __fadd_rn(__fmul_rn(y, ga), be);                       // *gamma+beta
        float d = __fmul_rn(__fsub_rn(y, vm), 0.5f);               // (y-v)/2.0 (exact)
        vm = __fadd_rn(vm, d);                                     // v += ...
        bool sp = (vm >= 1.0f);
        out[(size_t)t * BEV + idx] = sp ? 1.0f : 0.0f;
        if (sp) vm = 0.0f;                                         // hard reset
    }
}

extern "C" void kernel_launch(void* const* d_in, const int* in_sizes, int n_in,
                              void* d_out, int out_size, void* d_ws, size_t ws_size,
                              hipStream_t stream) {
    (void)in_sizes; (void)n_in; (void)out_size; (void)ws_size;
    const float* x  = (const float*)d_in[0];
    const float* W  = (const float*)d_in[1];
    const float* g  = (const float*)d_in[2];
    const float* bb = (const float*)d_in[3];
    float* ws = (float*)d_ws;        // fully overwritten by k_stats before use

    k_stats<<<E, 256, 0, stream>>>(x, W, ws);
    k_main<<<BEV / 256, 256, 0, stream>>>(x, W, g, bb, ws, (float*)d_out);
}